// Round 12
// baseline (23.070 us; speedup 1.0000x reference)
//
#include <hip/hip_runtime.h>
#include <hip/hip_bf16.h>
#include <math.h>

// MultiVariateAttention: out[b,u] = exp(mvn_logpdf(x[b]; mu[u], diag(s[u])))
// B = U = 4096, D = 16, fp32 in/out.
//
// R12 = R11 (fused 32u-tile kernel, 22.5us) + ONE lever: occupancy.
//   BB 512 -> 256 shrinks LDS 36.6 -> 20.6 KB (x-tile was the binder);
//   __launch_bounds__(256,5) caps VGPR at ~102 (~85 live, no spills) ->
//   5 blocks/CU = 20 waves/CU (was 4/16). More independent
//   ds_read->pk_fma-chain->exp2->store pipelines per SIMD to hide the
//   per-iteration serial dependency + store backpressure.

#define TPB 256
#define DD  16
#define UB  32     // u's per block
#define BB  256    // b's per block; grid (128, 16) = 2048 blocks

typedef float v2f __attribute__((ext_vector_type(2)));

static constexpr float L2E   = 1.4426950408889634f;   // log2(e)
static constexpr float HL2PI = 0.91893853320467274f;  // 0.5*ln(2*pi)

__global__ __launch_bounds__(TPB, 5) void mva_tile(
    const float* __restrict__ x,      // [B,1,D]
    const float* __restrict__ units,  // [U,D]
    const float* __restrict__ attn,   // [U,D,D]
    float* __restrict__ out,          // [B,U]
    int U)
{
    const int tid    = threadIdx.x;
    const int u_base = blockIdx.x * UB;
    const int b_base = blockIdx.y * BB;

    __shared__ float xs[BB][DD];          // 16 KB
    __shared__ float a1L[DD][UB + 2];     // +2 pad: float2-aligned, low conflict
    __shared__ float a2L[DD][UB + 2];
    __shared__ float biasL[UB];

    // ---- stage x tile (coalesced float4, 4 per thread) ----
    const float* xb = x + (size_t)b_base * DD;
#pragma unroll
    for (int r = 0; r < (BB * DD) / (TPB * 4); ++r) {  // 4 iters
        const int q = (r * TPB + tid) * 4;
        *reinterpret_cast<float4*>(&xs[0][0] + q) =
            *reinterpret_cast<const float4*>(xb + q);
    }

    // ---- param gather: 512 (u,d)-pairs over 256 threads (2 d's each) ----
    {
        const int ul = tid >> 3;          // 0..31  local u
        const int d0 = (tid & 7) * 2;     // 0,2,..,14
        const int u  = u_base + ul;
        float2 m = *reinterpret_cast<const float2*>(units + (size_t)u * DD + d0);
        const float* ar = attn + (size_t)u * DD * DD;
        float s0 = fmaxf(ar[d0 * (DD + 1)], 1e-6f);
        float s1 = fmaxf(ar[(d0 + 1) * (DD + 1)], 1e-6f);
        float w0 = 1.f / (s0 * s0);
        float w1 = 1.f / (s1 * s1);
        a1L[d0][ul]     = L2E * m.x * w0;
        a2L[d0][ul]     = -0.5f * L2E * w0;
        a1L[d0 + 1][ul] = L2E * m.y * w1;
        a2L[d0 + 1][ul] = -0.5f * L2E * w1;
        float bn = -0.5f * (m.x * m.x * w0 + m.y * m.y * w1)
                 - (logf(s0) + logf(s1));
        bn += __shfl_xor(bn, 1, 8);
        bn += __shfl_xor(bn, 2, 8);
        bn += __shfl_xor(bn, 4, 8);
        if ((tid & 7) == 0) biasL[ul] = L2E * (bn - DD * HL2PI);
    }
    __syncthreads();

    // ---- pull this thread's u-pair params into registers (packed) ----
    const int up = tid & 15;              // u-pair index: u = u_base + up*2
    const int br = tid >> 4;              // b-row offset 0..15
    v2f a1p[DD], a2p[DD];
#pragma unroll
    for (int d = 0; d < DD; ++d) {
        a1p[d] = *reinterpret_cast<const v2f*>(&a1L[d][up * 2]);
        a2p[d] = *reinterpret_cast<const v2f*>(&a2L[d][up * 2]);
    }
    const v2f biasp = *reinterpret_cast<const v2f*>(&biasL[up * 2]);

    // ---- main loop: 16 iters x 16 concurrent b-rows; stores stream ----
    float* orow = out + (size_t)b_base * U + u_base + up * 2;
#pragma unroll 2
    for (int it = 0; it < BB / 16; ++it) {
        const int b = it * 16 + br;
        v2f acc = biasp;
#pragma unroll
        for (int j = 0; j < 4; ++j) {
            // 16-lane groups share one address -> LDS broadcast; 2-way max.
            float4 xv = *reinterpret_cast<const float4*>(&xs[b][4 * j]);
            const int d = 4 * j;
            v2f xx, t;
            xx = (v2f){xv.x, xv.x};
            t   = __builtin_elementwise_fma(xx, a2p[d + 0], a1p[d + 0]);
            acc = __builtin_elementwise_fma(xx, t, acc);
            xx = (v2f){xv.y, xv.y};
            t   = __builtin_elementwise_fma(xx, a2p[d + 1], a1p[d + 1]);
            acc = __builtin_elementwise_fma(xx, t, acc);
            xx = (v2f){xv.z, xv.z};
            t   = __builtin_elementwise_fma(xx, a2p[d + 2], a1p[d + 2]);
            acc = __builtin_elementwise_fma(xx, t, acc);
            xx = (v2f){xv.w, xv.w};
            t   = __builtin_elementwise_fma(xx, a2p[d + 3], a1p[d + 3]);
            acc = __builtin_elementwise_fma(xx, t, acc);
        }
        float2 o;
        o.x = __builtin_amdgcn_exp2f(acc[0]);
        o.y = __builtin_amdgcn_exp2f(acc[1]);
        *reinterpret_cast<float2*>(orow + (size_t)b * U) = o;
    }
}

extern "C" void kernel_launch(void* const* d_in, const int* in_sizes, int n_in,
                              void* d_out, int out_size, void* d_ws, size_t ws_size,
                              hipStream_t stream) {
    const float* x     = (const float*)d_in[0];  // [B,1,D]
    const float* units = (const float*)d_in[1];  // [U,D]
    const float* attn  = (const float*)d_in[2];  // [U,D,D]
    float* out = (float*)d_out;

    const int B = in_sizes[0] / DD;  // 4096
    const int U = in_sizes[1] / DD;  // 4096

    dim3 grid(U / UB, B / BB);       // (128, 16) = 2048 blocks
    mva_tile<<<grid, TPB, 0, stream>>>(x, units, attn, out, U);
}